// Round 1
// baseline (165.455 us; speedup 1.0000x reference)
//
#include <hip/hip_runtime.h>
#include <math.h>

// RWKV WKV forward — single fused kernel.
// B=8, T=2048, H=768. NC=32 chunks of L=64.
// Block = 32 chunks x 32 h = 1024 threads; grid = (H/32, B) = (24, 8) = 192 blocks.
// Phase A: each thread builds its chunk's local (a,b,e) aggregate.
// Scan:    Hillis-Steele inclusive scan over chunks in LDS (5 steps, ping-pong).
//          Uniform decay shift w*L*2^s per step is exact because all chunks
//          have identical length L.
// Phase C: each thread replays its chunk from the exclusive prefix, writing out.
// No workspace, no extra dispatches, no global aggregate round-trip.

#define B_  8
#define T_  2048
#define H_  768
#define NC_ 32
#define L_  64
#define HG_ 32                   // h-slice per block
#define NT_ (NC_ * HG_)          // 1024 threads

__global__ __launch_bounds__(NT_) void wkv_fused(
    const float* __restrict__ key, const float* __restrict__ val,
    const float* __restrict__ time_decay, const float* __restrict__ time_first,
    float* __restrict__ out)
{
    // ping-pong scan buffers: 2 * 3 * 32 * 32 * 4B = 24 KB LDS
    __shared__ float sa[2][NC_][HG_];
    __shared__ float sb[2][NC_][HG_];
    __shared__ float se[2][NC_][HG_];

    const int tid = threadIdx.x;
    const int c   = tid >> 5;          // chunk 0..31
    const int ho  = tid & 31;          // h within slice
    const int h   = blockIdx.x * HG_ + ho;
    const int b   = blockIdx.y;

    const float w = -__expf(time_decay[h]);
    const float u = time_first[h];

    const size_t base = ((size_t)b * T_ + (size_t)c * L_) * H_ + h;
    const float* kp = key + base;
    const float* vp = val + base;

    // ---------------- Phase A: local chunk aggregate ----------------
    // Invariant: true A = a * e^e, true B = bb * e^e.
    float a = 0.f, bb = 0.f, e = -INFINITY;
#pragma unroll 4
    for (int t = 0; t < L_; ++t) {
        const float kt = kp[(size_t)t * H_];
        const float vt = vp[(size_t)t * H_];
        const float ew = e + w;
        const float m2 = fmaxf(ew, kt);
        const float s1 = __expf(ew - m2);
        const float s2 = __expf(kt - m2);
        a  = fmaf(s1, a,  s2 * vt);
        bb = fmaf(s1, bb, s2);
        e  = m2;
    }

    int cur = 0;
    sa[cur][c][ho] = a; sb[cur][c][ho] = bb; se[cur][c][ho] = e;
    __syncthreads();

    // ---------------- Inclusive Hillis-Steele scan over chunks ----------------
    // combine(prefix_earlier, segment_later):
    //   earlier exponent shifted by decay of the later segment: wL * 2^s
    const float wL = w * (float)L_;
#pragma unroll
    for (int s = 0; s < 5; ++s) {
        const int d = 1 << s;
        float na = sa[cur][c][ho];
        float nb = sb[cur][c][ho];
        float ne = se[cur][c][ho];
        if (c >= d) {
            const float pa = sa[cur][c - d][ho];
            const float pb = sb[cur][c - d][ho];
            const float pe = se[cur][c - d][ho] + wL * (float)d;
            const float m  = fmaxf(pe, ne);
            const float x  = __expf(pe - m);
            const float y  = __expf(ne - m);
            na = fmaf(pa, x, na * y);
            nb = fmaf(pb, x, nb * y);
            ne = m;
        }
        sa[cur ^ 1][c][ho] = na;
        sb[cur ^ 1][c][ho] = nb;
        se[cur ^ 1][c][ho] = ne;
        __syncthreads();
        cur ^= 1;
    }

    // exclusive prefix = incoming state for chunk c
    float ra = 0.f, rb = 0.f, re = -INFINITY;
    if (c > 0) {
        ra = sa[cur][c - 1][ho];
        rb = sb[cur][c - 1][ho];
        re = se[cur][c - 1][ho];
    }

    // ---------------- Phase C: replay chunk, emit outputs ----------------
    float* op = out + base;
#pragma unroll 4
    for (int t = 0; t < L_; ++t) {
        const float kt = kp[(size_t)t * H_];
        const float vt = vp[(size_t)t * H_];

        // output at this timestep (state BEFORE update)
        const float uk = u + kt;
        const float m1 = fmaxf(re, uk);
        const float wt = __expf(uk - m1);
        const float sc = __expf(re - m1);
        const float num = fmaf(ra, sc, wt * vt);
        const float den = fmaf(rb, sc, wt);
        op[(size_t)t * H_] = num / den;

        // state update
        const float ew = re + w;
        const float m2 = fmaxf(ew, kt);
        const float s1 = __expf(ew - m2);
        const float s2 = __expf(kt - m2);
        ra = fmaf(s1, ra, s2 * vt);
        rb = fmaf(s1, rb, s2);
        re = m2;
    }
}

extern "C" void kernel_launch(void* const* d_in, const int* in_sizes, int n_in,
                              void* d_out, int out_size, void* d_ws, size_t ws_size,
                              hipStream_t stream) {
    const float* key = (const float*)d_in[0];
    const float* val = (const float*)d_in[1];
    const float* td  = (const float*)d_in[2];
    const float* tf  = (const float*)d_in[3];
    float* out = (float*)d_out;

    dim3 grid(H_ / HG_, B_);   // 24 x 8 = 192 blocks, 1024 threads each
    wkv_fused<<<grid, NT_, 0, stream>>>(key, val, td, tf, out);
}